// Round 12
// baseline (1940.414 us; speedup 1.0000x reference)
//
#include <hip/hip_runtime.h>
#include <math.h>

// Problem constants
#define BB 32768
#define DD 64
#define CC 64
#define HH 1024
#define LL 6
#define SPLIT 32
#define NIN 96
#define EPSV 1e-5f

typedef short short8 __attribute__((ext_vector_type(8)));
typedef float f32x4 __attribute__((ext_vector_type(4)));
typedef unsigned short u16;

// fp32 -> bf16 round-to-nearest-even (finite inputs)
__device__ __forceinline__ u16 f2bf(float f) {
    union { float f; unsigned int u; } c; c.f = f;
    unsigned int u = c.u + 0x7FFFu + ((c.u >> 16) & 1u);
    return (u16)(u >> 16);
}

__device__ __forceinline__ void gl_lds16(const u16* g, u16* l) {
    __builtin_amdgcn_global_load_lds(
        (const __attribute__((address_space(1))) unsigned int*)g,
        (__attribute__((address_space(3))) unsigned int*)l, 16, 0, 0);
}

#define DSR(dst, addr, off) \
    asm volatile("ds_read_b128 %0, %1 offset:" #off : "=&v"(dst) : "v"(addr))

// ---------------------------------------------------------------------------
// Transpose + convert: dst[c][r] (bf16, row stride Rpad) = src[r][c] (f32)
// ---------------------------------------------------------------------------
__global__ void transpose_cvt_kernel(const float* __restrict__ src, u16* __restrict__ dst,
                                     int R, int C, int Rpad,
                                     long long sstride, long long dstride)
{
    __shared__ float tile[32][33];
    const float* s = src + (size_t)blockIdx.z * sstride;
    u16* d = dst + (size_t)blockIdx.z * dstride;
    int r0 = blockIdx.x * 32, c0 = blockIdx.y * 32;
    int tc = threadIdx.x & 31, tr = threadIdx.x >> 5;   // 32 x 8
#pragma unroll
    for (int i = 0; i < 4; ++i) {
        int r = r0 + tr + i * 8;
        tile[tr + i * 8][tc] = (r < R) ? s[(size_t)r * C + c0 + tc] : 0.f;
    }
    __syncthreads();
#pragma unroll
    for (int i = 0; i < 4; ++i) {
        int cc = tr + i * 8;
        d[(size_t)(c0 + cc) * Rpad + r0 + tc] = f2bf(tile[tc][cc]);
    }
}

// ---------------------------------------------------------------------------
// One-time: fill Ain cond columns (32..95) + zero pad (96..127), all BB rows.
// ---------------------------------------------------------------------------
__global__ __launch_bounds__(256)
void init_ain_cond_kernel(const float* __restrict__ cond, u16* __restrict__ Ain)
{
    int t = blockIdx.x * 256 + threadIdx.x;   // over BB*96
    int c = t % 96, r = t / 96;
    Ain[(size_t)r * 128 + 32 + c] = (c < CC) ? f2bf(cond[(size_t)r * CC + c]) : (u16)0;
}

// One-time (layer 0): fill Ain keep columns (0..31) from x.
__global__ __launch_bounds__(256)
void build_keep_kernel(const float* __restrict__ x, u16* __restrict__ Ain, int keep_off)
{
    int t = blockIdx.x * 256 + threadIdx.x;   // over BB*32
    int c = t & 31, r = t >> 5;
    Ain[(size_t)r * 128 + c] = f2bf(x[(size_t)r * DD + 2 * c + keep_off]);
}

// ---------------------------------------------------------------------------
// GEMM2 + fused partial-GEMM3: h2 = relu(h1 @ W2t^T + b2) stays IN LDS/regs
// (never written to global); the epilogue computes this block's partial
// st_part[bx][bm:bm+256][0:64] = h2_tile @ wst[bn:bn+256][:]  (f32).
// Main loop = round-11 barrier-free K-tile interior (K=1024 fixed).
// wst (256x64 slice, 32 KB) is DMA-staged into the dead sA-buf0 region
// during the LAST K-tile (covered by the loop-end vmcnt(0)) using gemm3's
// slot-order staging (DMA slot order == B-fragment order). Per m-block the
// existing scratch write yields relu'd row-major bf16 -> re-read as MFMA
// A-frags; 8 MFMA; cross-wn accumulation via LDS atomicAdd into st_block
// (f32, row stride 72 => quads hit disjoint bank groups, 2-way max).
// Block-exclusive plain store to st_part[bx] (no global atomics).
// LDS carve (131072 B): main loop sA=[0,64K) sB=[64K,128K);
// epilogue: W=[0,32K), st_block=[32K,106496), scr=[106496,124928).
// ---------------------------------------------------------------------------
__global__ __launch_bounds__(512, 2)
void gemm2_fused(const u16* __restrict__ A,     // h1 [BB][1024] bf16
                 const u16* __restrict__ Bt,    // w2t [1024][1024] bf16 N-major
                 const float* __restrict__ bias,// b2 [1024]
                 const u16* __restrict__ Wst,   // wstt layer slice [64][1024]
                 float* __restrict__ st_part)   // [4][BB][64] f32
{
    __shared__ u16 LDSBUF[65536];               // 128 KB
    const unsigned sAb = (unsigned)(size_t)(__attribute__((address_space(3))) u16*)&LDSBUF[0];
    const unsigned sBb = sAb + 65536;           // byte offset of sB region

    const int t = threadIdx.x;
    const int w = t >> 6, lane = t & 63;
    const int lane16 = lane & 15, quad = lane >> 4;
    const int wm = w >> 2, wn = w & 3;          // 2 x 4 waves, wave tile 128x64

    // XCD swizzle: grid = nby x 4, col index fastest within an XCD
    int id = blockIdx.x;
    int nby = gridDim.x >> 2;
    int xcd = id & 7, slot = id >> 3;
    int bx = slot & 3, byq = slot >> 2;
    int by = xcd * (nby >> 3) + byq;
    const int bm = by * 256, bn = bx * 256;

    // stage one half-tile (16 entries = 16 KB; 2 gl_lds per wave)
    auto stage_half = [&](int kt, int op, int s, int buf) {
        int k0 = kt * 64 + s * 32 + quad * 8;
#pragma unroll
        for (int r = 0; r < 2; ++r) {
            int i = r * 8 + w;
            int e = s * 16 + i;
            if (op == 0) {
                const u16* g = A + (size_t)(bm + i * 16 + lane16) * 1024 + k0;
                gl_lds16(g, &LDSBUF[buf * 16384 + e * 512]);
            } else {
                const u16* g = Bt + (size_t)(bn + i * 16 + lane16) * 1024 + k0;
                gl_lds16(g, &LDSBUF[32768 + buf * 16384 + e * 512]);
            }
        }
    };

    // stage wst slice (rows bn..bn+256 of the h-dim): 32 entries -> [0,32K)
    auto stage_W = [&]() {
#pragma unroll
        for (int r = 0; r < 4; ++r) {
            int e = r * 8 + w;                  // s = e>>2 (h-chunk), jg = e&3
            int s = e >> 2, jg = e & 3;
            const u16* g = Wst + (size_t)(jg * 16 + lane16) * HH + bn + s * 32 + quad * 8;
            gl_lds16(g, &LDSBUF[e * 512]);
        }
    };

    f32x4 acc[8][4];
#pragma unroll
    for (int a = 0; a < 8; ++a)
#pragma unroll
        for (int b = 0; b < 4; ++b) acc[a][b] = (f32x4){0.f, 0.f, 0.f, 0.f};

    const unsigned aoff = (unsigned)(wm * 8 * 1024 + lane * 16);   // wm*8 entries
    const unsigned boff = (unsigned)(wn * 4 * 1024 + lane * 16);   // wn*4 entries

    // ---- prologue: stage tile 0 ----
    stage_half(0, 0, 0, 0);
    stage_half(0, 1, 0, 0);
    stage_half(0, 0, 1, 0);
    stage_half(0, 1, 1, 0);
    asm volatile("s_waitcnt vmcnt(0)");
    __builtin_amdgcn_s_barrier();

    short8 af[4], ag[4], bf[4], bg[4];
    for (int kt = 0; kt < 16; ++kt) {
        const unsigned base = (unsigned)((kt & 1) << 15);
        const unsigned aA0 = sAb + base + aoff;
        const unsigned aB0 = sBb + base + boff;
        const unsigned aA1 = aA0 + 16384;
        const unsigned aB1 = aB0 + 16384;
        const int nb = (kt + 1) & 1;
        const bool more = (kt + 1 < 16);

        DSR(bf[0], aB0, 0); DSR(bf[1], aB0, 1024);
        DSR(bf[2], aB0, 2048); DSR(bf[3], aB0, 3072);
        DSR(af[0], aA0, 0); DSR(af[1], aA0, 1024);
        DSR(af[2], aA0, 2048); DSR(af[3], aA0, 3072);
        if (more) { stage_half(kt + 1, 0, 0, nb); stage_half(kt + 1, 1, 0, nb); }
        else      { stage_W(); }               // wst -> dead sA-buf0 region
        DSR(ag[0], aA0, 4096); DSR(ag[1], aA0, 5120);
        DSR(ag[2], aA0, 6144); DSR(ag[3], aA0, 7168);
        asm volatile("s_waitcnt lgkmcnt(4)");
        __builtin_amdgcn_sched_barrier(0);
        __builtin_amdgcn_s_setprio(1);
#pragma unroll
        for (int a = 0; a < 4; ++a)
#pragma unroll
            for (int b = 0; b < 4; ++b)
                acc[a][b] = __builtin_amdgcn_mfma_f32_16x16x32_bf16(af[a], bf[b], acc[a][b], 0, 0, 0);
        __builtin_amdgcn_s_setprio(0);

        if (more) { stage_half(kt + 1, 0, 1, nb); stage_half(kt + 1, 1, 1, nb); }
        DSR(bg[0], aB1, 0); DSR(bg[1], aB1, 1024);
        DSR(bg[2], aB1, 2048); DSR(bg[3], aB1, 3072);
        DSR(af[0], aA1, 0); DSR(af[1], aA1, 1024);
        DSR(af[2], aA1, 2048); DSR(af[3], aA1, 3072);
        asm volatile("s_waitcnt lgkmcnt(8)");
        __builtin_amdgcn_sched_barrier(0);
        __builtin_amdgcn_s_setprio(1);
#pragma unroll
        for (int a = 0; a < 4; ++a)
#pragma unroll
            for (int b = 0; b < 4; ++b)
                acc[4 + a][b] = __builtin_amdgcn_mfma_f32_16x16x32_bf16(ag[a], bf[b], acc[4 + a][b], 0, 0, 0);
        __builtin_amdgcn_s_setprio(0);

        DSR(ag[0], aA1, 4096); DSR(ag[1], aA1, 5120);
        DSR(ag[2], aA1, 6144); DSR(ag[3], aA1, 7168);
        asm volatile("s_waitcnt lgkmcnt(4)");
        __builtin_amdgcn_sched_barrier(0);
        __builtin_amdgcn_s_setprio(1);
#pragma unroll
        for (int a = 0; a < 4; ++a)
#pragma unroll
            for (int b = 0; b < 4; ++b)
                acc[a][b] = __builtin_amdgcn_mfma_f32_16x16x32_bf16(af[a], bg[b], acc[a][b], 0, 0, 0);
        __builtin_amdgcn_s_setprio(0);

        asm volatile("s_waitcnt lgkmcnt(0)");
        __builtin_amdgcn_sched_barrier(0);
        __builtin_amdgcn_s_setprio(1);
#pragma unroll
        for (int a = 0; a < 4; ++a)
#pragma unroll
            for (int b = 0; b < 4; ++b)
                acc[4 + a][b] = __builtin_amdgcn_mfma_f32_16x16x32_bf16(ag[a], bg[b], acc[4 + a][b], 0, 0, 0);
        __builtin_amdgcn_s_setprio(0);

        asm volatile("s_waitcnt vmcnt(0)");
        __builtin_amdgcn_s_barrier();
    }
    __syncthreads();                           // main loop done; W staged & drained

    // ---- zero st_block (f32[256][72] at byte 32768) ----
    constexpr int STB = 72;
    float* stb = (float*)(LDSBUF + 16384);
    for (int i = t; i < 256 * STB; i += 512) stb[i] = 0.f;
    __syncthreads();

    // ---- B-frags from W: wave's 64-h slice x 64 cols (8 x short8) ----
    short8 wb[2][4];
#pragma unroll
    for (int ks = 0; ks < 2; ++ks)
#pragma unroll
        for (int jg = 0; jg < 4; ++jg)
            wb[ks][jg] = *(const short8*)(LDSBUF + (size_t)(((wn * 2 + ks) * 4 + jg) * 512 + lane * 8));

    // ---- per m-block: scr write (relu'd bf16) -> A-frags -> 8 MFMA -> ds add
    constexpr int ES = 72;                     // shorts per scratch row
    float bv[4];
#pragma unroll
    for (int b = 0; b < 4; ++b) bv[b] = bias[bn + wn * 64 + b * 16 + lane16];
    u16* scr = LDSBUF + 53248 + w * 1152;      // 16 x 72 shorts per wave

#pragma unroll
    for (int m = 0; m < 8; ++m) {
#pragma unroll
        for (int b = 0; b < 4; ++b)
#pragma unroll
            for (int r = 0; r < 4; ++r) {
                float v = fmaxf(acc[m][b][r] + bv[b], 0.f);
                scr[(quad * 4 + r) * ES + b * 16 + lane16] = f2bf(v);
            }
        // A-frags: row = lane16, k(local 64) = ks*32 + quad*8 (+e)
        short8 a0 = *(const short8*)(scr + lane16 * ES + quad * 8);
        short8 a1 = *(const short8*)(scr + lane16 * ES + 32 + quad * 8);
        f32x4 stacc[4];
#pragma unroll
        for (int jt = 0; jt < 4; ++jt) stacc[jt] = (f32x4){0.f, 0.f, 0.f, 0.f};
#pragma unroll
        for (int jt = 0; jt < 4; ++jt) {
            stacc[jt] = __builtin_amdgcn_mfma_f32_16x16x32_bf16(a0, wb[0][jt], stacc[jt], 0, 0, 0);
            stacc[jt] = __builtin_amdgcn_mfma_f32_16x16x32_bf16(a1, wb[1][jt], stacc[jt], 0, 0, 0);
        }
        int rowbase = wm * 128 + m * 16 + quad * 4;
#pragma unroll
        for (int jt = 0; jt < 4; ++jt)
#pragma unroll
            for (int r = 0; r < 4; ++r)
                atomicAdd(&stb[(rowbase + r) * STB + jt * 16 + lane16], stacc[jt][r]);
    }
    __syncthreads();

    // ---- store st_block -> st_part[bx] (block-exclusive rows) ----
    float* dst = st_part + ((size_t)bx * BB + bm) * 64;
#pragma unroll
    for (int r8 = 0; r8 < 8; ++r8) {
        int row = r8 * 32 + (t >> 4), c4 = (t & 15) * 4;
        f32x4 v = *(const f32x4*)(stb + row * STB + c4);
        *(f32x4*)(dst + (size_t)row * 64 + c4) = v;
    }
}

// ---------------------------------------------------------------------------
// GEMM1 specialization: K=128 FIXED (round-10, kept: ~60 us total win).
// ---------------------------------------------------------------------------
__global__ __launch_bounds__(512, 2)
void gemm1_once(const u16* __restrict__ A,    // [M][128] bf16 row-major
                const u16* __restrict__ Bt,   // [1024][128] bf16 N-major
                const float* __restrict__ bias,
                u16* __restrict__ Cc)         // [M][1024] bf16 out
{
    __shared__ u16 sA[2][32 * 512];
    __shared__ u16 sB[2][32 * 512];

    const int t = threadIdx.x;
    const int w = t >> 6, lane = t & 63;
    const int lane16 = lane & 15, quad = lane >> 4;
    const int wm = w >> 2, wn = w & 3;

    int id = blockIdx.x;
    int nby = gridDim.x >> 2;
    int xcd = id & 7, slot = id >> 3;
    int bx = slot & 3, byq = slot >> 2;
    int by = xcd * (nby >> 3) + byq;
    const int bm = by * 256, bn = bx * 256;

    auto stage_half = [&](int kt, int op, int s, int buf) {
        int k0 = kt * 64 + s * 32 + quad * 8;
#pragma unroll
        for (int r = 0; r < 2; ++r) {
            int i = r * 8 + w;
            int e = s * 16 + i;
            if (op == 0) {
                const u16* g = A + (size_t)(bm + i * 16 + lane16) * 128 + k0;
                gl_lds16(g, &sA[buf][e * 512]);
            } else {
                const u16* g = Bt + (size_t)(bn + i * 16 + lane16) * 128 + k0;
                gl_lds16(g, &sB[buf][e * 512]);
            }
        }
    };

    f32x4 acc[8][4];
#pragma unroll
    for (int a = 0; a < 8; ++a)
#pragma unroll
        for (int b = 0; b < 4; ++b) acc[a][b] = (f32x4){0.f, 0.f, 0.f, 0.f};

    const unsigned sAb = (unsigned)(size_t)(__attribute__((address_space(3))) u16*)&sA[0][0];
    const unsigned sBb = (unsigned)(size_t)(__attribute__((address_space(3))) u16*)&sB[0][0];
    const unsigned aoff = (unsigned)(wm * 8 * 1024 + lane * 16);
    const unsigned boff = (unsigned)(wn * 4 * 1024 + lane * 16);

#pragma unroll
    for (int kt = 0; kt < 2; ++kt) {
        stage_half(kt, 0, 0, kt);
        stage_half(kt, 1, 0, kt);
        stage_half(kt, 0, 1, kt);
        stage_half(kt, 1, 1, kt);
    }
    __syncthreads();

    short8 af[4], ag[4], bf[4], bg[4];
#pragma unroll
    for (int kt = 0; kt < 2; ++kt) {
        const unsigned base = (unsigned)(kt << 15);
        const unsigned aA0 = sAb + base + aoff;
        const unsigned aB0 = sBb + base + boff;
        const unsigned aA1 = aA0 + 16384;
        const unsigned aB1 = aB0 + 16384;

        DSR(bf[0], aB0, 0); DSR(bf[1], aB0, 1024);
        DSR(bf[2], aB0, 2048); DSR(bf[3], aB0, 3072);
        DSR(af[0], aA0, 0); DSR(af[1], aA0, 1024);
        DSR(af[2], aA0, 2048); DSR(af[3], aA0, 3072);
        DSR(ag[0], aA0, 4096); DSR(ag[1], aA0, 5120);
        DSR(ag[2], aA0, 6144); DSR(ag[3], aA0, 7168);
        asm volatile("s_waitcnt lgkmcnt(4)");
        __builtin_amdgcn_sched_barrier(0);
        __builtin_amdgcn_s_setprio(1);
#pragma unroll
        for (int a = 0; a < 4; ++a)
#pragma unroll
            for (int b = 0; b < 4; ++b)
                acc[a][b] = __builtin_amdgcn_mfma_f32_16x16x32_bf16(af[a], bf[b], acc[a][b], 0, 0, 0);
        __builtin_amdgcn_s_setprio(0);

        DSR(bg[0], aB1, 0); DSR(bg[1], aB1, 1024);
        DSR(bg[2], aB1, 2048); DSR(bg[3], aB1, 3072);
        DSR(af[0], aA1, 0); DSR(af[1], aA1, 1024);
        DSR(af[2], aA1, 2048); DSR(af[3], aA1, 3072);
        asm volatile("s_waitcnt lgkmcnt(8)");
        __builtin_amdgcn_sched_barrier(0);
        __builtin_amdgcn_s_setprio(1);
#pragma unroll
        for (int a = 0; a < 4; ++a)
#pragma unroll
            for (int b = 0; b < 4; ++b)
                acc[4 + a][b] = __builtin_amdgcn_mfma_f32_16x16x32_bf16(ag[a], bf[b], acc[4 + a][b], 0, 0, 0);
        __builtin_amdgcn_s_setprio(0);

        DSR(ag[0], aA1, 4096); DSR(ag[1], aA1, 5120);
        DSR(ag[2], aA1, 6144); DSR(ag[3], aA1, 7168);
        asm volatile("s_waitcnt lgkmcnt(4)");
        __builtin_amdgcn_sched_barrier(0);
        __builtin_amdgcn_s_setprio(1);
#pragma unroll
        for (int a = 0; a < 4; ++a)
#pragma unroll
            for (int b = 0; b < 4; ++b)
                acc[a][b] = __builtin_amdgcn_mfma_f32_16x16x32_bf16(af[a], bg[b], acc[a][b], 0, 0, 0);
        __builtin_amdgcn_s_setprio(0);

        asm volatile("s_waitcnt lgkmcnt(0)");
        __builtin_amdgcn_sched_barrier(0);
        __builtin_amdgcn_s_setprio(1);
#pragma unroll
        for (int a = 0; a < 4; ++a)
#pragma unroll
            for (int b = 0; b < 4; ++b)
                acc[4 + a][b] = __builtin_amdgcn_mfma_f32_16x16x32_bf16(ag[a], bg[b], acc[4 + a][b], 0, 0, 0);
        __builtin_amdgcn_s_setprio(0);
    }
    __syncthreads();

    constexpr int ES = 72;
    float bv[4];
#pragma unroll
    for (int b = 0; b < 4; ++b) bv[b] = bias[bn + wn * 64 + b * 16 + lane16];
    u16* scr = ((u16*)sB) + w * (16 * ES);
#pragma unroll
    for (int a = 0; a < 8; ++a) {
#pragma unroll
        for (int b = 0; b < 4; ++b)
#pragma unroll
            for (int r = 0; r < 4; ++r) {
                float v = fmaxf(acc[a][b][r] + bv[b], 0.f);
                scr[(quad * 4 + r) * ES + b * 16 + lane16] = f2bf(v);
            }
#pragma unroll
        for (int ch = 0; ch < 2; ++ch) {
            int row = ch * 8 + (lane >> 3), colc = (lane & 7) * 8;
            short8 v = *(const short8*)(scr + row * ES + colc);
            *(short8*)(Cc + (size_t)(bm + wm * 128 + a * 16 + row) * 1024 + bn + wn * 64 + colc) = v;
        }
    }
}

// ---------------------------------------------------------------------------
// Coupling (replaces gemm3): sums the 4 st partials, applies tanh/exp
// coupling to x, accumulates log_det and BN stats. Tail logic verbatim
// from the old gemm3_coupling.
// ---------------------------------------------------------------------------
__global__ __launch_bounds__(512)
void coupling_kernel(const float* __restrict__ st_part,   // [4][BB][64]
                     const float* __restrict__ bs, const float* __restrict__ bt,
                     float* __restrict__ x, float* __restrict__ log_det,
                     float* __restrict__ stat_sum, float* __restrict__ stat_sumsq,
                     int keep_off)
{
    __shared__ float ssum[8][64], ssum2[8][64];
    const int t = threadIdx.x;
    const int w = t >> 6, lane = t & 63;
    const int bm = blockIdx.x * 128;

    const int f = lane;
    const bool is_chg = ((f & 1) != keep_off);
    const int j = f >> 1;
    float bsj = 0.f, btj = 0.f;
    if (is_chg) { bsj = bs[j]; btj = bt[j]; }

    float lsum = 0.f, lsum2 = 0.f;
    for (int i = 0; i < 16; ++i) {
        int grow = bm + w * 16 + i;
        float xv = x[(size_t)grow * DD + f];
        float ld = 0.f;
        if (is_chg) {
            float s_raw = 0.f, t_raw = 0.f;
#pragma unroll
            for (int p = 0; p < 4; ++p) {
                const float* q = st_part + ((size_t)p * BB + grow) * 64;
                s_raw += q[j];
                t_raw += q[32 + j];
            }
            float ls = tanhf(s_raw + bsj);
            float tv = t_raw + btj;
            xv = xv * expf(ls) + tv;
            x[(size_t)grow * DD + f] = xv;
            ld = ls;
        }
        for (int off = 32; off > 0; off >>= 1) ld += __shfl_down(ld, off, 64);
        if (f == 0) log_det[grow] += ld;
        lsum  += xv;
        lsum2 += xv * xv;
    }

    ssum[w][f]  = lsum;
    ssum2[w][f] = lsum2;
    __syncthreads();
    if (t < 64) {
        float a = 0.f, b = 0.f;
#pragma unroll
        for (int g = 0; g < 8; ++g) { a += ssum[g][t]; b += ssum2[g][t]; }
        atomicAdd(stat_sum + t, a);
        atomicAdd(stat_sumsq + t, b);
    }
}

// ---------------------------------------------------------------------------
// BN normalize (scale/shift computed in-block from raw stats); optionally
// writes bf16 keep-columns of next layer's Ain.
// ---------------------------------------------------------------------------
__global__ __launch_bounds__(256)
void normalize_kernel(const float* __restrict__ xin, float* __restrict__ xout,
                      const float* __restrict__ stat_sum, const float* __restrict__ stat_sumsq,
                      const float* __restrict__ bn_w, const float* __restrict__ bn_b,
                      float* __restrict__ log_det,
                      u16* __restrict__ Ain, int off_next)
{
    __shared__ float sscale[64], sshift[64], scsum;
    int t = threadIdx.x;
    if (t < 64) {
        const float invB = 1.f / (float)BB;
        float mean = stat_sum[t] * invB;
        float var  = stat_sumsq[t] * invB - mean * mean;
        float inv  = rsqrtf(var + EPSV);
        float wv   = bn_w[t];
        float sc   = inv * wv;
        sscale[t] = sc;
        sshift[t] = bn_b[t] - mean * sc;
        float lg = logf(fabsf(wv));
        for (int off = 32; off > 0; off >>= 1) lg += __shfl_down(lg, off, 64);
        if (t == 0) scsum = lg;
    }
    __syncthreads();

    int idx = blockIdx.x * blockDim.x + t;     // over B*64/4
    int f0 = (idx & 15) * 4;
    int row = idx >> 4;
    float4 v = ((const float4*)xin)[idx];
    v.x = v.x * sscale[f0 + 0] + sshift[f0 + 0];
    v.y = v.y * sscale[f0 + 1] + sshift[f0 + 1];
    v.z = v.z * sscale[f0 + 2] + sshift[f0 + 2];
    v.w = v.w * sscale[f0 + 3] + sshift[f0 + 3];
    ((float4*)xout)[idx] = v;
    if ((idx & 15) == 0) log_det[row] += scsum;
    if (Ain) {
        float a0 = off_next ? v.y : v.x;
        float a1 = off_next ? v.w : v.z;
        ushort2 u; u.x = f2bf(a0); u.y = f2bf(a1);
        *(ushort2*)(Ain + (size_t)row * 128 + (f0 >> 1)) = u;
    }
}

// ---------------------------------------------------------------------------
extern "C" void kernel_launch(void* const* d_in, const int* in_sizes, int n_in,
                              void* d_out, int out_size, void* d_ws, size_t ws_size,
                              hipStream_t stream)
{
    const float* z    = (const float*)d_in[0];
    const float* cond = (const float*)d_in[1];
    const float* W1   = (const float*)d_in[2];
    const float* b1   = (const float*)d_in[3];
    const float* W2   = (const float*)d_in[4];
    const float* b2   = (const float*)d_in[5];
    const float* Ws   = (const float*)d_in[6];
    const float* bs   = (const float*)d_in[7];
    const float* Wt   = (const float*)d_in[8];
    const float* bt   = (const float*)d_in[9];
    const float* bn_w = (const float*)d_in[10];
    const float* bn_b = (const float*)d_in[11];

    float* out_x  = (float*)d_out;
    float* out_ld = out_x + (size_t)BB * DD;

    // ---- workspace ----
    char* p = (char*)d_ws;
    size_t used = 0;
    auto alloc = [&](size_t bytes) { void* q = p + used; used += (bytes + 255) & ~(size_t)255; return q; };

    float* xbuf = (float*)alloc((size_t)BB * DD * 4);
    u16*   w1t  = (u16*)alloc((size_t)LL * HH * 128 * 2);
    u16*   w2t  = (u16*)alloc((size_t)LL * HH * HH * 2);
    u16*   wstt = (u16*)alloc((size_t)LL * 64 * HH * 2);
    u16*   Ain  = (u16*)alloc((size_t)BB * 128 * 2);
    float* stat_sum   = (float*)alloc(64 * 4);
    float* stat_sumsq = (float*)alloc(64 * 4);
    u16*   h1   = (u16*)alloc((size_t)BB * HH * 2);
    float* st_part = (float*)alloc((size_t)4 * BB * 64 * 4);   // 32 MB

    // ---- init ----
    hipMemcpyAsync(xbuf, z, (size_t)BB * DD * sizeof(float), hipMemcpyDeviceToDevice, stream);
    hipMemsetAsync(out_ld, 0, (size_t)BB * sizeof(float), stream);

    transpose_cvt_kernel<<<dim3(128/32, HH/32, LL), 256, 0, stream>>>(
        W1, w1t, NIN, HH, 128, (long long)NIN * HH, (long long)HH * 128);
    transpose_cvt_kernel<<<dim3(HH/32, HH/32, LL), 256, 0, stream>>>(
        W2, w2t, HH, HH, HH, (long long)HH * HH, (long long)HH * HH);
    transpose_cvt_kernel<<<dim3(HH/32, SPLIT/32, LL), 256, 0, stream>>>(
        Ws, wstt, HH, SPLIT, HH, (long long)HH * SPLIT, (long long)64 * HH);
    transpose_cvt_kernel<<<dim3(HH/32, SPLIT/32, LL), 256, 0, stream>>>(
        Wt, wstt + (size_t)SPLIT * HH, HH, SPLIT, HH, (long long)HH * SPLIT, (long long)64 * HH);

    init_ain_cond_kernel<<<BB * 96 / 256, 256, 0, stream>>>(cond, Ain);
    build_keep_kernel<<<BB * 32 / 256, 256, 0, stream>>>(xbuf, Ain, 0);

    for (int l = 0; l < LL; ++l) {
        const int off = l & 1;
        hipMemsetAsync(stat_sum, 0, 2 * 64 * sizeof(float), stream);

        // GEMM1: h1 = relu(Ain @ W1t^T + b1)   M=BB, K=128 (specialized)
        gemm1_once<<<(BB / 256) * 4, 512, 0, stream>>>(
            Ain, w1t + (size_t)l * HH * 128, b1 + (size_t)l * HH, h1);

        // GEMM2 + fused partial GEMM3 (h2 never hits global)
        gemm2_fused<<<(BB / 256) * 4, 512, 0, stream>>>(
            h1, w2t + (size_t)l * HH * HH, b2 + (size_t)l * HH,
            wstt + (size_t)l * 64 * HH, st_part);

        // Coupling + stats (replaces gemm3)
        coupling_kernel<<<BB / 128, 512, 0, stream>>>(
            st_part, bs + (size_t)l * SPLIT, bt + (size_t)l * SPLIT,
            xbuf, out_ld, stat_sum, stat_sumsq, off);

        float* xout = (l == LL - 1) ? out_x : xbuf;
        u16* ain_next = (l < LL - 1) ? Ain : nullptr;
        normalize_kernel<<<(BB * DD / 4) / 256, 256, 0, stream>>>(
            xbuf, xout, stat_sum, stat_sumsq,
            bn_w + (size_t)l * DD, bn_b + (size_t)l * DD,
            out_ld, ain_next, (l + 1) & 1);
    }
}

// Round 13
// 943.484 us; speedup vs baseline: 2.0566x; 2.0566x over previous
//
#include <hip/hip_runtime.h>
#include <math.h>

// Problem constants
#define BB 32768
#define DD 64
#define CC 64
#define HH 1024
#define LL 6
#define SPLIT 32
#define NIN 96
#define EPSV 1e-5f

typedef short short8 __attribute__((ext_vector_type(8)));
typedef float f32x4 __attribute__((ext_vector_type(4)));
typedef unsigned short u16;

// fp32 -> bf16 round-to-nearest-even (finite inputs)
__device__ __forceinline__ u16 f2bf(float f) {
    union { float f; unsigned int u; } c; c.f = f;
    unsigned int u = c.u + 0x7FFFu + ((c.u >> 16) & 1u);
    return (u16)(u >> 16);
}

__device__ __forceinline__ void gl_lds16(const u16* g, u16* l) {
    __builtin_amdgcn_global_load_lds(
        (const __attribute__((address_space(1))) unsigned int*)g,
        (__attribute__((address_space(3))) unsigned int*)l, 16, 0, 0);
}

#define DSR(dst, addr, off) \
    asm volatile("ds_read_b128 %0, %1 offset:" #off : "=&v"(dst) : "v"(addr))

// ---------------------------------------------------------------------------
// Transpose + convert: dst[c][r] (bf16, row stride Rpad) = src[r][c] (f32)
// ---------------------------------------------------------------------------
__global__ void transpose_cvt_kernel(const float* __restrict__ src, u16* __restrict__ dst,
                                     int R, int C, int Rpad,
                                     long long sstride, long long dstride)
{
    __shared__ float tile[32][33];
    const float* s = src + (size_t)blockIdx.z * sstride;
    u16* d = dst + (size_t)blockIdx.z * dstride;
    int r0 = blockIdx.x * 32, c0 = blockIdx.y * 32;
    int tc = threadIdx.x & 31, tr = threadIdx.x >> 5;   // 32 x 8
#pragma unroll
    for (int i = 0; i < 4; ++i) {
        int r = r0 + tr + i * 8;
        tile[tr + i * 8][tc] = (r < R) ? s[(size_t)r * C + c0 + tc] : 0.f;
    }
    __syncthreads();
#pragma unroll
    for (int i = 0; i < 4; ++i) {
        int cc = tr + i * 8;
        d[(size_t)(c0 + cc) * Rpad + r0 + tc] = f2bf(tile[tc][cc]);
    }
}

// ---------------------------------------------------------------------------
// One-time: fill Ain cond columns (32..95) + zero pad (96..127), all BB rows.
// ---------------------------------------------------------------------------
__global__ __launch_bounds__(256)
void init_ain_cond_kernel(const float* __restrict__ cond, u16* __restrict__ Ain)
{
    int t = blockIdx.x * 256 + threadIdx.x;   // over BB*96
    int c = t % 96, r = t / 96;
    Ain[(size_t)r * 128 + 32 + c] = (c < CC) ? f2bf(cond[(size_t)r * CC + c]) : (u16)0;
}

// One-time (layer 0): fill Ain keep columns (0..31) from x.
__global__ __launch_bounds__(256)
void build_keep_kernel(const float* __restrict__ x, u16* __restrict__ Ain, int keep_off)
{
    int t = blockIdx.x * 256 + threadIdx.x;   // over BB*32
    int c = t & 31, r = t >> 5;
    Ain[(size_t)r * 128 + c] = f2bf(x[(size_t)r * DD + 2 * c + keep_off]);
}

// ---------------------------------------------------------------------------
// Tiled bf16 MFMA GEMM: C = relu(A @ Bt^T + bias), N = 1024 fixed.
// BM=256 x BN=256, 8 waves (2x4), wave tile 128x64 (acc 8x4).
// FROZEN at the round-4 structure (best measured: 83 us @ M=32768,K=1024).
// m201-style phases, BK=64 K-tiles, 2-deep double-buffered LDS (128 KB,
// 1 block/CU), entry-contiguous layout (conflict-free per counters).
// Used for GEMM2 only; GEMM1 (K=128) has a dedicated kernel below.
// ---------------------------------------------------------------------------
__global__ __launch_bounds__(512, 2)
void gemm_tiled(const u16* __restrict__ A,    // [M][K] bf16 row-major (chunk-local)
                const u16* __restrict__ Bt,   // [1024][K] bf16 N-major
                const float* __restrict__ bias,
                u16* __restrict__ Cc,         // [M][1024] bf16 out
                int K)
{
    __shared__ u16 sA[2][32 * 512];    // 64 KB: per buf 32 entries (ksub*16 + rowtile)
    __shared__ u16 sB[2][32 * 512];    // 64 KB: per buf 32 entries (ksub*16 + coltile)

    const int t = threadIdx.x;
    const int w = t >> 6, lane = t & 63;
    const int lane16 = lane & 15, quad = lane >> 4;
    const int wm = w >> 2, wn = w & 3;          // 2 x 4 waves, wave tile 128x64

    // XCD swizzle: grid = nby x 4, col index fastest within an XCD
    int id = blockIdx.x;
    int nby = gridDim.x >> 2;
    int xcd = id & 7, slot = id >> 3;
    int bx = slot & 3, byq = slot >> 2;
    int by = xcd * (nby >> 3) + byq;
    const int bm = by * 256, bn = bx * 256;

    const int ntile = K >> 6;                  // BK=64 tiles

    // stage one half-tile (16 entries = 16 KB; 2 gl_lds per wave)
    auto stage_half = [&](int kt, int op, int s, int buf) {
        int k0 = kt * 64 + s * 32 + quad * 8;
#pragma unroll
        for (int r = 0; r < 2; ++r) {
            int i = r * 8 + w;
            int e = s * 16 + i;
            if (op == 0) {
                const u16* g = A + (size_t)(bm + i * 16 + lane16) * K + k0;
                gl_lds16(g, &sA[buf][e * 512]);
            } else {
                const u16* g = Bt + (size_t)(bn + i * 16 + lane16) * K + k0;
                gl_lds16(g, &sB[buf][e * 512]);
            }
        }
    };

    f32x4 acc[8][4];
#pragma unroll
    for (int a = 0; a < 8; ++a)
#pragma unroll
        for (int b = 0; b < 4; ++b) acc[a][b] = (f32x4){0.f, 0.f, 0.f, 0.f};

    // LDS byte addresses (as3 ptrtoint = group-segment offset)
    const unsigned sAb = (unsigned)(size_t)(__attribute__((address_space(3))) u16*)&sA[0][0];
    const unsigned sBb = (unsigned)(size_t)(__attribute__((address_space(3))) u16*)&sB[0][0];
    const unsigned aoff = (unsigned)(wm * 8 * 1024 + lane * 16);   // wm*8 entries
    const unsigned boff = (unsigned)(wn * 4 * 1024 + lane * 16);   // wn*4 entries

    // ---- prologue: stage tile 0 (4 half-tiles, 8 loads/wave) ----
    stage_half(0, 0, 0, 0);
    stage_half(0, 1, 0, 0);
    stage_half(0, 0, 1, 0);
    stage_half(0, 1, 1, 0);
    asm volatile("s_waitcnt vmcnt(4)");        // ksub0 halves landed
    __builtin_amdgcn_s_barrier();

    short8 af[4], ag[4], bf[4], bg[4];
    for (int kt = 0; kt < ntile; ++kt) {
        const unsigned base = (unsigned)((kt & 1) << 15);       // *32768 B
        const unsigned aA0 = sAb + base + aoff;
        const unsigned aB0 = sBb + base + boff;
        const unsigned aA1 = aA0 + 16384;
        const unsigned aB1 = aB0 + 16384;
        const int nk = (kt + 1 < ntile) ? kt + 1 : kt;          // dummy on last
        const int nb = (kt + 1) & 1;

        // ================= phase 0: (a0-3) x b x k0 =================
        DSR(bf[0], aB0, 0); DSR(bf[1], aB0, 1024);
        DSR(bf[2], aB0, 2048); DSR(bf[3], aB0, 3072);
        DSR(af[0], aA0, 0); DSR(af[1], aA0, 1024);
        DSR(af[2], aA0, 2048); DSR(af[3], aA0, 3072);
        stage_half(nk, 0, 0, nb);              // H(kt+1, A, ks0)
        __builtin_amdgcn_s_barrier();
        asm volatile("s_waitcnt lgkmcnt(0)");
        __builtin_amdgcn_sched_barrier(0);
        __builtin_amdgcn_s_setprio(1);
#pragma unroll
        for (int a = 0; a < 4; ++a)
#pragma unroll
            for (int b = 0; b < 4; ++b)
                acc[a][b] = __builtin_amdgcn_mfma_f32_16x16x32_bf16(af[a], bf[b], acc[a][b], 0, 0, 0);
        __builtin_amdgcn_s_setprio(0);
        __builtin_amdgcn_s_barrier();

        // ================= phase 1: (a4-7) x b x k0 =================
        DSR(ag[0], aA0, 4096); DSR(ag[1], aA0, 5120);
        DSR(ag[2], aA0, 6144); DSR(ag[3], aA0, 7168);
        stage_half(nk, 1, 0, nb);              // H(kt+1, B, ks0)
        __builtin_amdgcn_s_barrier();
        asm volatile("s_waitcnt lgkmcnt(0)");
        __builtin_amdgcn_sched_barrier(0);
        __builtin_amdgcn_s_setprio(1);
#pragma unroll
        for (int a = 0; a < 4; ++a)
#pragma unroll
            for (int b = 0; b < 4; ++b)
                acc[4 + a][b] = __builtin_amdgcn_mfma_f32_16x16x32_bf16(ag[a], bf[b], acc[4 + a][b], 0, 0, 0);
        __builtin_amdgcn_s_setprio(0);
        asm volatile("s_waitcnt vmcnt(4)");    // this tile's ksub1 halves landed
        __builtin_amdgcn_s_barrier();

        // ================= phase 2: (a0-3) x b x k1 =================
        DSR(bg[0], aB1, 0); DSR(bg[1], aB1, 1024);
        DSR(bg[2], aB1, 2048); DSR(bg[3], aB1, 3072);
        DSR(af[0], aA1, 0); DSR(af[1], aA1, 1024);
        DSR(af[2], aA1, 2048); DSR(af[3], aA1, 3072);
        stage_half(nk, 0, 1, nb);              // H(kt+1, A, ks1)
        __builtin_amdgcn_s_barrier();
        asm volatile("s_waitcnt lgkmcnt(0)");
        __builtin_amdgcn_sched_barrier(0);
        __builtin_amdgcn_s_setprio(1);
#pragma unroll
        for (int a = 0; a < 4; ++a)
#pragma unroll
            for (int b = 0; b < 4; ++b)
                acc[a][b] = __builtin_amdgcn_mfma_f32_16x16x32_bf16(af[a], bg[b], acc[a][b], 0, 0, 0);
        __builtin_amdgcn_s_setprio(0);
        __builtin_amdgcn_s_barrier();

        // ================= phase 3: (a4-7) x b x k1 =================
        DSR(ag[0], aA1, 4096); DSR(ag[1], aA1, 5120);
        DSR(ag[2], aA1, 6144); DSR(ag[3], aA1, 7168);
        stage_half(nk, 1, 1, nb);              // H(kt+1, B, ks1)
        __builtin_amdgcn_s_barrier();
        asm volatile("s_waitcnt lgkmcnt(0)");
        __builtin_amdgcn_sched_barrier(0);
        __builtin_amdgcn_s_setprio(1);
#pragma unroll
        for (int a = 0; a < 4; ++a)
#pragma unroll
            for (int b = 0; b < 4; ++b)
                acc[4 + a][b] = __builtin_amdgcn_mfma_f32_16x16x32_bf16(ag[a], bg[b], acc[4 + a][b], 0, 0, 0);
        __builtin_amdgcn_s_setprio(0);
        asm volatile("s_waitcnt vmcnt(4)");    // next tile's ksub0 halves landed
        __builtin_amdgcn_s_barrier();
    }
    __syncthreads();                           // drains DMA (incl. dummy); LDS reusable

    // ---- epilogue: bias+relu+f2bf via per-wave scratch, coalesced stores ----
    constexpr int ES = 72;                     // shorts per scratch row
    float bv[4];
#pragma unroll
    for (int b = 0; b < 4; ++b) bv[b] = bias[bn + wn * 64 + b * 16 + lane16];
    u16* scr = ((u16*)sB) + w * (16 * ES);     // 2304 B per wave
#pragma unroll
    for (int a = 0; a < 8; ++a) {
#pragma unroll
        for (int b = 0; b < 4; ++b)
#pragma unroll
            for (int r = 0; r < 4; ++r) {
                float v = fmaxf(acc[a][b][r] + bv[b], 0.f);
                scr[(quad * 4 + r) * ES + b * 16 + lane16] = f2bf(v);
            }
#pragma unroll
        for (int ch = 0; ch < 2; ++ch) {
            int row = ch * 8 + (lane >> 3), colc = (lane & 7) * 8;
            short8 v = *(const short8*)(scr + row * ES + colc);
            *(short8*)(Cc + (size_t)(bm + wm * 128 + a * 16 + row) * 1024 + bn + wn * 64 + colc) = v;
        }
    }
}

// ---------------------------------------------------------------------------
// GEMM1 specialization: K=128 FIXED (round-10, kept: ~60 us total win).
// Stage everything up-front, one __syncthreads, straight-line compute with
// counted lgkmcnt chaining, zero barriers.
// ---------------------------------------------------------------------------
__global__ __launch_bounds__(512, 2)
void gemm1_once(const u16* __restrict__ A,    // [M][128] bf16 row-major
                const u16* __restrict__ Bt,   // [1024][128] bf16 N-major
                const float* __restrict__ bias,
                u16* __restrict__ Cc)         // [M][1024] bf16 out
{
    __shared__ u16 sA[2][32 * 512];    // buf kt: 32 entries (ksub*16 + rowtile)
    __shared__ u16 sB[2][32 * 512];

    const int t = threadIdx.x;
    const int w = t >> 6, lane = t & 63;
    const int lane16 = lane & 15, quad = lane >> 4;
    const int wm = w >> 2, wn = w & 3;          // 2 x 4 waves, wave tile 128x64

    int id = blockIdx.x;
    int nby = gridDim.x >> 2;
    int xcd = id & 7, slot = id >> 3;
    int bx = slot & 3, byq = slot >> 2;
    int by = xcd * (nby >> 3) + byq;
    const int bm = by * 256, bn = bx * 256;

    auto stage_half = [&](int kt, int op, int s, int buf) {
        int k0 = kt * 64 + s * 32 + quad * 8;
#pragma unroll
        for (int r = 0; r < 2; ++r) {
            int i = r * 8 + w;
            int e = s * 16 + i;
            if (op == 0) {
                const u16* g = A + (size_t)(bm + i * 16 + lane16) * 128 + k0;
                gl_lds16(g, &sA[buf][e * 512]);
            } else {
                const u16* g = Bt + (size_t)(bn + i * 16 + lane16) * 128 + k0;
                gl_lds16(g, &sB[buf][e * 512]);
            }
        }
    };

    f32x4 acc[8][4];
#pragma unroll
    for (int a = 0; a < 8; ++a)
#pragma unroll
        for (int b = 0; b < 4; ++b) acc[a][b] = (f32x4){0.f, 0.f, 0.f, 0.f};

    const unsigned sAb = (unsigned)(size_t)(__attribute__((address_space(3))) u16*)&sA[0][0];
    const unsigned sBb = (unsigned)(size_t)(__attribute__((address_space(3))) u16*)&sB[0][0];
    const unsigned aoff = (unsigned)(wm * 8 * 1024 + lane * 16);
    const unsigned boff = (unsigned)(wn * 4 * 1024 + lane * 16);

    // ---- stage EVERYTHING (2 K-tiles x A,B x 2 ksubs = 16 loads/wave) ----
#pragma unroll
    for (int kt = 0; kt < 2; ++kt) {
        stage_half(kt, 0, 0, kt);
        stage_half(kt, 1, 0, kt);
        stage_half(kt, 0, 1, kt);
        stage_half(kt, 1, 1, kt);
    }
    __syncthreads();                           // drains DMA; all data resident

    short8 af[4], ag[4], bf[4], bg[4];
#pragma unroll
    for (int kt = 0; kt < 2; ++kt) {
        const unsigned base = (unsigned)(kt << 15);
        const unsigned aA0 = sAb + base + aoff;
        const unsigned aB0 = sBb + base + boff;
        const unsigned aA1 = aA0 + 16384;
        const unsigned aB1 = aB0 + 16384;

        DSR(bf[0], aB0, 0); DSR(bf[1], aB0, 1024);
        DSR(bf[2], aB0, 2048); DSR(bf[3], aB0, 3072);
        DSR(af[0], aA0, 0); DSR(af[1], aA0, 1024);
        DSR(af[2], aA0, 2048); DSR(af[3], aA0, 3072);
        DSR(ag[0], aA0, 4096); DSR(ag[1], aA0, 5120);
        DSR(ag[2], aA0, 6144); DSR(ag[3], aA0, 7168);
        asm volatile("s_waitcnt lgkmcnt(4)");  // bf+af done (ag may fly)
        __builtin_amdgcn_sched_barrier(0);
        __builtin_amdgcn_s_setprio(1);
#pragma unroll
        for (int a = 0; a < 4; ++a)
#pragma unroll
            for (int b = 0; b < 4; ++b)
                acc[a][b] = __builtin_amdgcn_mfma_f32_16x16x32_bf16(af[a], bf[b], acc[a][b], 0, 0, 0);
        __builtin_amdgcn_s_setprio(0);

        DSR(bg[0], aB1, 0); DSR(bg[1], aB1, 1024);
        DSR(bg[2], aB1, 2048); DSR(bg[3], aB1, 3072);
        DSR(af[0], aA1, 0); DSR(af[1], aA1, 1024);
        DSR(af[2], aA1, 2048); DSR(af[3], aA1, 3072);
        asm volatile("s_waitcnt lgkmcnt(8)");  // ag done (bg+af may fly)
        __builtin_amdgcn_sched_barrier(0);
        __builtin_amdgcn_s_setprio(1);
#pragma unroll
        for (int a = 0; a < 4; ++a)
#pragma unroll
            for (int b = 0; b < 4; ++b)
                acc[4 + a][b] = __builtin_amdgcn_mfma_f32_16x16x32_bf16(ag[a], bf[b], acc[4 + a][b], 0, 0, 0);
        __builtin_amdgcn_s_setprio(0);

        DSR(ag[0], aA1, 4096); DSR(ag[1], aA1, 5120);
        DSR(ag[2], aA1, 6144); DSR(ag[3], aA1, 7168);
        asm volatile("s_waitcnt lgkmcnt(4)");  // bg+af (ksub1) done
        __builtin_amdgcn_sched_barrier(0);
        __builtin_amdgcn_s_setprio(1);
#pragma unroll
        for (int a = 0; a < 4; ++a)
#pragma unroll
            for (int b = 0; b < 4; ++b)
                acc[a][b] = __builtin_amdgcn_mfma_f32_16x16x32_bf16(af[a], bg[b], acc[a][b], 0, 0, 0);
        __builtin_amdgcn_s_setprio(0);

        asm volatile("s_waitcnt lgkmcnt(0)");  // ag (ksub1) done
        __builtin_amdgcn_sched_barrier(0);
        __builtin_amdgcn_s_setprio(1);
#pragma unroll
        for (int a = 0; a < 4; ++a)
#pragma unroll
            for (int b = 0; b < 4; ++b)
                acc[4 + a][b] = __builtin_amdgcn_mfma_f32_16x16x32_bf16(ag[a], bg[b], acc[4 + a][b], 0, 0, 0);
        __builtin_amdgcn_s_setprio(0);
    }
    __syncthreads();                           // all LDS reads done; reuse as scratch

    // ---- epilogue: identical to gemm_tiled ----
    constexpr int ES = 72;
    float bv[4];
#pragma unroll
    for (int b = 0; b < 4; ++b) bv[b] = bias[bn + wn * 64 + b * 16 + lane16];
    u16* scr = ((u16*)sB) + w * (16 * ES);
#pragma unroll
    for (int a = 0; a < 8; ++a) {
#pragma unroll
        for (int b = 0; b < 4; ++b)
#pragma unroll
            for (int r = 0; r < 4; ++r) {
                float v = fmaxf(acc[a][b][r] + bv[b], 0.f);
                scr[(quad * 4 + r) * ES + b * 16 + lane16] = f2bf(v);
            }
#pragma unroll
        for (int ch = 0; ch < 2; ++ch) {
            int row = ch * 8 + (lane >> 3), colc = (lane & 7) * 8;
            short8 v = *(const short8*)(scr + row * ES + colc);
            *(short8*)(Cc + (size_t)(bm + wm * 128 + a * 16 + row) * 1024 + bn + wn * 64 + colc) = v;
        }
    }
}

// ---------------------------------------------------------------------------
// Fused GEMM3 + coupling: tall-skinny streaming form (round-9, kept).
// B (wst, 128 KB) staged to LDS once; A streams global->register; 32
// barrier-free K-steps; coupling/stats tail unchanged.
// ---------------------------------------------------------------------------
__global__ __launch_bounds__(512)
void gemm3_coupling(const u16* __restrict__ A,    // h2 chunk [CH][1024]
                    const u16* __restrict__ Bt,   // wst [64][1024]
                    const float* __restrict__ bs, const float* __restrict__ bt,
                    float* __restrict__ x, float* __restrict__ log_det,
                    float* __restrict__ stat_sum, float* __restrict__ stat_sumsq,
                    int keep_off, int row0)
{
    constexpr int ST_STRIDE = 66;
    __shared__ u16 sB[128 * 512];                    // 128 KB: entry e = s*4+j
    __shared__ float ssum[8][64], ssum2[8][64];
    float* sst = (float*)sB;                         // 128*66*4 = 33.8 KB < 128 KB

    const int t = threadIdx.x;
    const int w = t >> 6, lane = t & 63;
    const int lane16 = lane & 15, quad = lane >> 4;
    const int bm = blockIdx.x * 128;

    // ---- stage all of B once: 128 entries (16 KB/wave, 16 gl_lds) ----
#pragma unroll
    for (int r = 0; r < 16; ++r) {
        int e = r * 8 + w;                           // s = e>>2, j = e&3
        int s = e >> 2, j = e & 3;
        const u16* g = Bt + (size_t)(j * 16 + lane16) * HH + s * 32 + quad * 8;
        gl_lds16(g, &sB[e * 512]);
    }

    f32x4 acc[4];
#pragma unroll
    for (int j = 0; j < 4; ++j) acc[j] = (f32x4){0.f, 0.f, 0.f, 0.f};

    const u16* Arow = A + (size_t)(bm + w * 16 + lane16) * HH + quad * 8;

    __syncthreads();                                 // B staged (drains DMA)

    // ---- main loop: 32 K-steps of 32, no barriers ----
#pragma unroll 4
    for (int s = 0; s < 32; ++s) {
        short8 af = *(const short8*)(Arow + s * 32);
        const u16* bb = sB + s * 2048 + lane * 8;    // entry (s*4+0), lane frag
#pragma unroll
        for (int j = 0; j < 4; ++j) {
            short8 bfr = *(const short8*)(bb + j * 512);
            acc[j] = __builtin_amdgcn_mfma_f32_16x16x32_bf16(af, bfr, acc[j], 0, 0, 0);
        }
    }
    __syncthreads();                                 // all B reads done; alias as sst

    // scatter acc -> LDS st tile (128 x 64)
#pragma unroll
    for (int j = 0; j < 4; ++j)
#pragma unroll
        for (int r = 0; r < 4; ++r)
            sst[(w * 16 + quad * 4 + r) * ST_STRIDE + j * 16 + lane16] = acc[j][r];
    __syncthreads();

    // coupling: wave w -> rows [w*16, w*16+16), lane = feature f
    const int f = lane;
    const bool is_chg = ((f & 1) != keep_off);
    const int j = f >> 1;
    float bsj = 0.f, btj = 0.f;
    if (is_chg) { bsj = bs[j]; btj = bt[j]; }

    float lsum = 0.f, lsum2 = 0.f;
    for (int i = 0; i < 16; ++i) {
        int crow = w * 16 + i;
        int grow = row0 + bm + crow;
        float xv = x[(size_t)grow * DD + f];
        float ld = 0.f;
        if (is_chg) {
            float s_raw = sst[crow * ST_STRIDE + j];
            float t_raw = sst[crow * ST_STRIDE + SPLIT + j];
            float ls = tanhf(s_raw + bsj);
            float tv = t_raw + btj;
            xv = xv * expf(ls) + tv;
            x[(size_t)grow * DD + f] = xv;
            ld = ls;
        }
        for (int off = 32; off > 0; off >>= 1) ld += __shfl_down(ld, off, 64);
        if (f == 0) log_det[grow] += ld;
        lsum  += xv;
        lsum2 += xv * xv;
    }

    ssum[w][f]  = lsum;
    ssum2[w][f] = lsum2;
    __syncthreads();
    if (t < 64) {
        float a = 0.f, b = 0.f;
#pragma unroll
        for (int g = 0; g < 8; ++g) { a += ssum[g][t]; b += ssum2[g][t]; }
        atomicAdd(stat_sum + t, a);
        atomicAdd(stat_sumsq + t, b);
    }
}

// ---------------------------------------------------------------------------
// BN normalize (scale/shift computed in-block from raw stats); optionally
// writes bf16 keep-columns of next layer's Ain.
// ---------------------------------------------------------------------------
__global__ __launch_bounds__(256)
void normalize_kernel(const float* __restrict__ xin, float* __restrict__ xout,
                      const float* __restrict__ stat_sum, const float* __restrict__ stat_sumsq,
                      const float* __restrict__ bn_w, const float* __restrict__ bn_b,
                      float* __restrict__ log_det,
                      u16* __restrict__ Ain, int off_next)
{
    __shared__ float sscale[64], sshift[64], scsum;
    int t = threadIdx.x;
    if (t < 64) {
        const float invB = 1.f / (float)BB;
        float mean = stat_sum[t] * invB;
        float var  = stat_sumsq[t] * invB - mean * mean;
        float inv  = rsqrtf(var + EPSV);
        float wv   = bn_w[t];
        float sc   = inv * wv;
        sscale[t] = sc;
        sshift[t] = bn_b[t] - mean * sc;
        float lg = logf(fabsf(wv));
        for (int off = 32; off > 0; off >>= 1) lg += __shfl_down(lg, off, 64);
        if (t == 0) scsum = lg;
    }
    __syncthreads();

    int idx = blockIdx.x * blockDim.x + t;     // over B*64/4
    int f0 = (idx & 15) * 4;
    int row = idx >> 4;
    float4 v = ((const float4*)xin)[idx];
    v.x = v.x * sscale[f0 + 0] + sshift[f0 + 0];
    v.y = v.y * sscale[f0 + 1] + sshift[f0 + 1];
    v.z = v.z * sscale[f0 + 2] + sshift[f0 + 2];
    v.w = v.w * sscale[f0 + 3] + sshift[f0 + 3];
    ((float4*)xout)[idx] = v;
    if ((idx & 15) == 0) log_det[row] += scsum;
    if (Ain) {
        float a0 = off_next ? v.y : v.x;
        float a1 = off_next ? v.w : v.z;
        ushort2 u; u.x = f2bf(a0); u.y = f2bf(a1);
        *(ushort2*)(Ain + (size_t)row * 128 + (f0 >> 1)) = u;
    }
}

// ---------------------------------------------------------------------------
extern "C" void kernel_launch(void* const* d_in, const int* in_sizes, int n_in,
                              void* d_out, int out_size, void* d_ws, size_t ws_size,
                              hipStream_t stream)
{
    const float* z    = (const float*)d_in[0];
    const float* cond = (const float*)d_in[1];
    const float* W1   = (const float*)d_in[2];
    const float* b1   = (const float*)d_in[3];
    const float* W2   = (const float*)d_in[4];
    const float* b2   = (const float*)d_in[5];
    const float* Ws   = (const float*)d_in[6];
    const float* bs   = (const float*)d_in[7];
    const float* Wt   = (const float*)d_in[8];
    const float* bt   = (const float*)d_in[9];
    const float* bn_w = (const float*)d_in[10];
    const float* bn_b = (const float*)d_in[11];

    float* out_x  = (float*)d_out;
    float* out_ld = out_x + (size_t)BB * DD;

    // ---- workspace: fixed part ~30.5 MB + h1/h2 (CH*4 KB) ----
    char* p = (char*)d_ws;
    size_t used = 0;
    auto alloc = [&](size_t bytes) { void* q = p + used; used += (bytes + 255) & ~(size_t)255; return q; };

    float* xbuf = (float*)alloc((size_t)BB * DD * 4);
    u16*   w1t  = (u16*)alloc((size_t)LL * HH * 128 * 2);
    u16*   w2t  = (u16*)alloc((size_t)LL * HH * HH * 2);
    u16*   wstt = (u16*)alloc((size_t)LL * 64 * HH * 2);
    u16*   Ain  = (u16*)alloc((size_t)BB * 128 * 2);
    float* stat_sum   = (float*)alloc(64 * 4);
    float* stat_sumsq = (float*)alloc(64 * 4);

    int CH = BB;
    while (CH > 8192 && used + (size_t)CH * 4096 + 4096 > ws_size) CH >>= 1;
    u16* h1 = (u16*)alloc((size_t)CH * HH * 2);
    u16* h2 = (u16*)alloc((size_t)CH * HH * 2);

    // ---- init ----
    hipMemcpyAsync(xbuf, z, (size_t)BB * DD * sizeof(float), hipMemcpyDeviceToDevice, stream);
    hipMemsetAsync(out_ld, 0, (size_t)BB * sizeof(float), stream);

    transpose_cvt_kernel<<<dim3(128/32, HH/32, LL), 256, 0, stream>>>(
        W1, w1t, NIN, HH, 128, (long long)NIN * HH, (long long)HH * 128);
    transpose_cvt_kernel<<<dim3(HH/32, HH/32, LL), 256, 0, stream>>>(
        W2, w2t, HH, HH, HH, (long long)HH * HH, (long long)HH * HH);
    transpose_cvt_kernel<<<dim3(HH/32, SPLIT/32, LL), 256, 0, stream>>>(
        Ws, wstt, HH, SPLIT, HH, (long long)HH * SPLIT, (long long)64 * HH);
    transpose_cvt_kernel<<<dim3(HH/32, SPLIT/32, LL), 256, 0, stream>>>(
        Wt, wstt + (size_t)SPLIT * HH, HH, SPLIT, HH, (long long)HH * SPLIT, (long long)64 * HH);

    init_ain_cond_kernel<<<BB * 96 / 256, 256, 0, stream>>>(cond, Ain);
    build_keep_kernel<<<BB * 32 / 256, 256, 0, stream>>>(xbuf, Ain, 0);

    for (int l = 0; l < LL; ++l) {
        const int off = l & 1;
        hipMemsetAsync(stat_sum, 0, 2 * 64 * sizeof(float), stream);

        for (int c = 0; c < BB / CH; ++c) {
            const int row0 = c * CH;

            // GEMM1: h1 = relu(Ain @ W1t^T + b1)   M=CH, K=128 (specialized)
            gemm1_once<<<(CH / 256) * 4, 512, 0, stream>>>(
                Ain + (size_t)row0 * 128, w1t + (size_t)l * HH * 128,
                b1 + (size_t)l * HH, h1);

            // GEMM2: h2 = relu(h1 @ W2t^T + b2)    M=CH, K=1024
            gemm_tiled<<<(CH / 256) * 4, 512, 0, stream>>>(
                h1, w2t + (size_t)l * HH * HH,
                b2 + (size_t)l * HH, h2, HH);

            // GEMM3 + coupling fused (streaming, B-in-LDS-once)
            gemm3_coupling<<<CH / 128, 512, 0, stream>>>(
                h2, wstt + (size_t)l * 64 * HH,
                bs + (size_t)l * SPLIT, bt + (size_t)l * SPLIT,
                xbuf, out_ld, stat_sum, stat_sumsq, off, row0);
        }

        float* xout = (l == LL - 1) ? out_x : xbuf;
        u16* ain_next = (l < LL - 1) ? Ain : nullptr;
        normalize_kernel<<<(BB * DD / 4) / 256, 256, 0, stream>>>(
            xbuf, xout, stat_sum, stat_sumsq,
            bn_w + (size_t)l * DD, bn_b + (size_t)l * DD,
            out_ld, ain_next, (l + 1) & 1);
    }
}

// Round 14
// 932.123 us; speedup vs baseline: 2.0817x; 1.0122x over previous
//
#include <hip/hip_runtime.h>
#include <math.h>

// Problem constants
#define BB 32768
#define DD 64
#define CC 64
#define HH 1024
#define LL 6
#define SPLIT 32
#define NIN 96
#define EPSV 1e-5f

typedef short short8 __attribute__((ext_vector_type(8)));
typedef float f32x4 __attribute__((ext_vector_type(4)));
typedef unsigned short u16;

// fp32 -> bf16 round-to-nearest-even (finite inputs)
__device__ __forceinline__ u16 f2bf(float f) {
    union { float f; unsigned int u; } c; c.f = f;
    unsigned int u = c.u + 0x7FFFu + ((c.u >> 16) & 1u);
    return (u16)(u >> 16);
}

__device__ __forceinline__ void gl_lds16(const u16* g, u16* l) {
    __builtin_amdgcn_global_load_lds(
        (const __attribute__((address_space(1))) unsigned int*)g,
        (__attribute__((address_space(3))) unsigned int*)l, 16, 0, 0);
}

#define DSR(dst, addr, off) \
    asm volatile("ds_read_b128 %0, %1 offset:" #off : "=&v"(dst) : "v"(addr))

// ---------------------------------------------------------------------------
// Transpose + convert: dst[c][r] (bf16, row stride Rpad) = src[r][c] (f32)
// ---------------------------------------------------------------------------
__global__ void transpose_cvt_kernel(const float* __restrict__ src, u16* __restrict__ dst,
                                     int R, int C, int Rpad,
                                     long long sstride, long long dstride)
{
    __shared__ float tile[32][33];
    const float* s = src + (size_t)blockIdx.z * sstride;
    u16* d = dst + (size_t)blockIdx.z * dstride;
    int r0 = blockIdx.x * 32, c0 = blockIdx.y * 32;
    int tc = threadIdx.x & 31, tr = threadIdx.x >> 5;   // 32 x 8
#pragma unroll
    for (int i = 0; i < 4; ++i) {
        int r = r0 + tr + i * 8;
        tile[tr + i * 8][tc] = (r < R) ? s[(size_t)r * C + c0 + tc] : 0.f;
    }
    __syncthreads();
#pragma unroll
    for (int i = 0; i < 4; ++i) {
        int cc = tr + i * 8;
        d[(size_t)(c0 + cc) * Rpad + r0 + tc] = f2bf(tile[tc][cc]);
    }
}

// ---------------------------------------------------------------------------
// One-time: fill Ain cond columns (32..95) + zero pad (96..127), all BB rows.
// ---------------------------------------------------------------------------
__global__ __launch_bounds__(256)
void init_ain_cond_kernel(const float* __restrict__ cond, u16* __restrict__ Ain)
{
    int t = blockIdx.x * 256 + threadIdx.x;   // over BB*96
    int c = t % 96, r = t / 96;
    Ain[(size_t)r * 128 + 32 + c] = (c < CC) ? f2bf(cond[(size_t)r * CC + c]) : (u16)0;
}

// One-time (layer 0): fill Ain keep columns (0..31) from x.
__global__ __launch_bounds__(256)
void build_keep_kernel(const float* __restrict__ x, u16* __restrict__ Ain, int keep_off)
{
    int t = blockIdx.x * 256 + threadIdx.x;   // over BB*32
    int c = t & 31, r = t >> 5;
    Ain[(size_t)r * 128 + c] = f2bf(x[(size_t)r * DD + 2 * c + keep_off]);
}

// ---------------------------------------------------------------------------
// Tiled bf16 MFMA GEMM: C = relu(A @ Bt^T + bias), N = 1024 fixed.
// BM=256 x BN=256, 8 waves (2x4), wave tile 128x64 (acc 8x4).
// NEW (this round): BK=32 K-tiles, 3-deep LDS buffers (96 KB, 1 block/CU),
// free-run interior (counted lgkmcnt chaining, no intra-tile barriers) +
// 2-TILE prefetch distance with counted tile-end vmcnt(4) (T4: tile kt+1's
// staging -- issued a full tile earlier -- must have landed; tile kt+2's 4
// loads stay in flight across the barrier). Write-safety: stage target
// (kt+2)%3 was last read in tile kt-1, behind two barriers. Tail tiles use
// vmcnt(0). Entry-contiguous layout (conflict-free ds_read_b128).
// Works for any K % 32 == 0 with ntile >= 2; used for GEMM2 (K=1024).
// ---------------------------------------------------------------------------
__global__ __launch_bounds__(512, 2)
void gemm_tiled(const u16* __restrict__ A,    // [M][K] bf16 row-major (chunk-local)
                const u16* __restrict__ Bt,   // [1024][K] bf16 N-major
                const float* __restrict__ bias,
                u16* __restrict__ Cc,         // [M][1024] bf16 out
                int K)
{
    __shared__ u16 sA[3][16 * 512];    // 48 KB: per buf 16 row-tile entries (1 KB)
    __shared__ u16 sB[3][16 * 512];    // 48 KB: per buf 16 col-tile entries

    const int t = threadIdx.x;
    const int w = t >> 6, lane = t & 63;
    const int lane16 = lane & 15, quad = lane >> 4;
    const int wm = w >> 2, wn = w & 3;          // 2 x 4 waves, wave tile 128x64

    // XCD swizzle: grid = nby x 4, col index fastest within an XCD
    int id = blockIdx.x;
    int nby = gridDim.x >> 2;
    int xcd = id & 7, slot = id >> 3;
    int bx = slot & 3, byq = slot >> 2;
    int by = xcd * (nby >> 3) + byq;
    const int bm = by * 256, bn = bx * 256;

    const int ntile = K >> 5;                  // BK=32 tiles

    // stage K-tile kt into buf: 32 entries (16 A + 16 B), 4 gl_lds per wave
    auto stage = [&](int kt, int buf) {
        int k0 = kt * 32 + quad * 8;
#pragma unroll
        for (int p = 0; p < 4; ++p) {
            int e = p * 8 + w;
            if (e < 16) {
                const u16* g = A + (size_t)(bm + e * 16 + lane16) * K + k0;
                gl_lds16(g, &sA[buf][e * 512]);
            } else {
                int j = e - 16;
                const u16* g = Bt + (size_t)(bn + j * 16 + lane16) * K + k0;
                gl_lds16(g, &sB[buf][j * 512]);
            }
        }
    };

    f32x4 acc[8][4];
#pragma unroll
    for (int a = 0; a < 8; ++a)
#pragma unroll
        for (int b = 0; b < 4; ++b) acc[a][b] = (f32x4){0.f, 0.f, 0.f, 0.f};

    // LDS byte addresses (as3 ptrtoint = group-segment offset)
    const unsigned sAb = (unsigned)(size_t)(__attribute__((address_space(3))) u16*)&sA[0][0];
    const unsigned sBb = (unsigned)(size_t)(__attribute__((address_space(3))) u16*)&sB[0][0];
    const unsigned aoff = (unsigned)(wm * 8 * 1024 + lane * 16);   // wm*8 entries
    const unsigned boff = (unsigned)(wn * 4 * 1024 + lane * 16);   // wn*4 entries

    // ---- prologue: stage tiles 0,1 (8 loads/wave) ----
    stage(0, 0);
    stage(1, 1);
    asm volatile("s_waitcnt vmcnt(4)");        // own stage(0) landed
    __builtin_amdgcn_s_barrier();              // everyone's stage(0) landed

    int cb = 0;                                // current buffer = kt % 3
    for (int kt = 0; kt < ntile; ++kt) {
        const unsigned aA = sAb + (unsigned)(cb * 16384) + aoff;
        const unsigned aB = sBb + (unsigned)(cb * 16384) + boff;
        int sb = cb - 1; if (sb < 0) sb = 2;   // (kt+2) % 3

        short8 af[4], ag[4], bf[4];
        DSR(bf[0], aB, 0);    DSR(bf[1], aB, 1024);
        DSR(bf[2], aB, 2048); DSR(bf[3], aB, 3072);
        DSR(af[0], aA, 0);    DSR(af[1], aA, 1024);
        DSR(af[2], aA, 2048); DSR(af[3], aA, 3072);
        if (kt + 2 < ntile) stage(kt + 2, sb); // 4 VMEM, lands >=1 full tile later
        DSR(ag[0], aA, 4096); DSR(ag[1], aA, 5120);
        DSR(ag[2], aA, 6144); DSR(ag[3], aA, 7168);

        asm volatile("s_waitcnt lgkmcnt(4)");  // bf+af done (ag may fly)
        __builtin_amdgcn_sched_barrier(0);
        __builtin_amdgcn_s_setprio(1);
#pragma unroll
        for (int a = 0; a < 4; ++a)
#pragma unroll
            for (int b = 0; b < 4; ++b)
                acc[a][b] = __builtin_amdgcn_mfma_f32_16x16x32_bf16(af[a], bf[b], acc[a][b], 0, 0, 0);
        __builtin_amdgcn_s_setprio(0);

        asm volatile("s_waitcnt lgkmcnt(0)");  // ag done
        __builtin_amdgcn_sched_barrier(0);
        __builtin_amdgcn_s_setprio(1);
#pragma unroll
        for (int a = 0; a < 4; ++a)
#pragma unroll
            for (int b = 0; b < 4; ++b)
                acc[4 + a][b] = __builtin_amdgcn_mfma_f32_16x16x32_bf16(ag[a], bf[b], acc[4 + a][b], 0, 0, 0);
        __builtin_amdgcn_s_setprio(0);

        // tile end: tile kt+1's staging landed (issued one full tile ago);
        // tile kt+2's 4 loads may remain in flight across the barrier (T4).
        if (kt + 2 < ntile) asm volatile("s_waitcnt vmcnt(4)");
        else                asm volatile("s_waitcnt vmcnt(0)");
        __builtin_amdgcn_s_barrier();

        cb = (cb == 2) ? 0 : cb + 1;
    }
    __syncthreads();                           // LDS reusable

    // ---- epilogue: bias+relu+f2bf via per-wave scratch, coalesced stores ----
    constexpr int ES = 72;                     // shorts per scratch row
    float bv[4];
#pragma unroll
    for (int b = 0; b < 4; ++b) bv[b] = bias[bn + wn * 64 + b * 16 + lane16];
    u16* scr = ((u16*)sB) + w * (16 * ES);     // 2304 B per wave
#pragma unroll
    for (int a = 0; a < 8; ++a) {
#pragma unroll
        for (int b = 0; b < 4; ++b)
#pragma unroll
            for (int r = 0; r < 4; ++r) {
                float v = fmaxf(acc[a][b][r] + bv[b], 0.f);
                scr[(quad * 4 + r) * ES + b * 16 + lane16] = f2bf(v);
            }
#pragma unroll
        for (int ch = 0; ch < 2; ++ch) {
            int row = ch * 8 + (lane >> 3), colc = (lane & 7) * 8;
            short8 v = *(const short8*)(scr + row * ES + colc);
            *(short8*)(Cc + (size_t)(bm + wm * 128 + a * 16 + row) * 1024 + bn + wn * 64 + colc) = v;
        }
    }
}

// ---------------------------------------------------------------------------
// GEMM1 specialization: K=128 FIXED (round-10, kept: ~60 us total win).
// Stage everything up-front, one __syncthreads, straight-line compute with
// counted lgkmcnt chaining, zero barriers.
// ---------------------------------------------------------------------------
__global__ __launch_bounds__(512, 2)
void gemm1_once(const u16* __restrict__ A,    // [M][128] bf16 row-major
                const u16* __restrict__ Bt,   // [1024][128] bf16 N-major
                const float* __restrict__ bias,
                u16* __restrict__ Cc)         // [M][1024] bf16 out
{
    __shared__ u16 sA[2][32 * 512];    // buf kt: 32 entries (ksub*16 + rowtile)
    __shared__ u16 sB[2][32 * 512];

    const int t = threadIdx.x;
    const int w = t >> 6, lane = t & 63;
    const int lane16 = lane & 15, quad = lane >> 4;
    const int wm = w >> 2, wn = w & 3;          // 2 x 4 waves, wave tile 128x64

    int id = blockIdx.x;
    int nby = gridDim.x >> 2;
    int xcd = id & 7, slot = id >> 3;
    int bx = slot & 3, byq = slot >> 2;
    int by = xcd * (nby >> 3) + byq;
    const int bm = by * 256, bn = bx * 256;

    auto stage_half = [&](int kt, int op, int s, int buf) {
        int k0 = kt * 64 + s * 32 + quad * 8;
#pragma unroll
        for (int r = 0; r < 2; ++r) {
            int i = r * 8 + w;
            int e = s * 16 + i;
            if (op == 0) {
                const u16* g = A + (size_t)(bm + i * 16 + lane16) * 128 + k0;
                gl_lds16(g, &sA[buf][e * 512]);
            } else {
                const u16* g = Bt + (size_t)(bn + i * 16 + lane16) * 128 + k0;
                gl_lds16(g, &sB[buf][e * 512]);
            }
        }
    };

    f32x4 acc[8][4];
#pragma unroll
    for (int a = 0; a < 8; ++a)
#pragma unroll
        for (int b = 0; b < 4; ++b) acc[a][b] = (f32x4){0.f, 0.f, 0.f, 0.f};

    const unsigned sAb = (unsigned)(size_t)(__attribute__((address_space(3))) u16*)&sA[0][0];
    const unsigned sBb = (unsigned)(size_t)(__attribute__((address_space(3))) u16*)&sB[0][0];
    const unsigned aoff = (unsigned)(wm * 8 * 1024 + lane * 16);
    const unsigned boff = (unsigned)(wn * 4 * 1024 + lane * 16);

    // ---- stage EVERYTHING (2 K-tiles x A,B x 2 ksubs = 16 loads/wave) ----
#pragma unroll
    for (int kt = 0; kt < 2; ++kt) {
        stage_half(kt, 0, 0, kt);
        stage_half(kt, 1, 0, kt);
        stage_half(kt, 0, 1, kt);
        stage_half(kt, 1, 1, kt);
    }
    __syncthreads();                           // drains DMA; all data resident

    short8 af[4], ag[4], bf[4], bg[4];
#pragma unroll
    for (int kt = 0; kt < 2; ++kt) {
        const unsigned base = (unsigned)(kt << 15);
        const unsigned aA0 = sAb + base + aoff;
        const unsigned aB0 = sBb + base + boff;
        const unsigned aA1 = aA0 + 16384;
        const unsigned aB1 = aB0 + 16384;

        DSR(bf[0], aB0, 0); DSR(bf[1], aB0, 1024);
        DSR(bf[2], aB0, 2048); DSR(bf[3], aB0, 3072);
        DSR(af[0], aA0, 0); DSR(af[1], aA0, 1024);
        DSR(af[2], aA0, 2048); DSR(af[3], aA0, 3072);
        DSR(ag[0], aA0, 4096); DSR(ag[1], aA0, 5120);
        DSR(ag[2], aA0, 6144); DSR(ag[3], aA0, 7168);
        asm volatile("s_waitcnt lgkmcnt(4)");  // bf+af done (ag may fly)
        __builtin_amdgcn_sched_barrier(0);
        __builtin_amdgcn_s_setprio(1);
#pragma unroll
        for (int a = 0; a < 4; ++a)
#pragma unroll
            for (int b = 0; b < 4; ++b)
                acc[a][b] = __builtin_amdgcn_mfma_f32_16x16x32_bf16(af[a], bf[b], acc[a][b], 0, 0, 0);
        __builtin_amdgcn_s_setprio(0);

        DSR(bg[0], aB1, 0); DSR(bg[1], aB1, 1024);
        DSR(bg[2], aB1, 2048); DSR(bg[3], aB1, 3072);
        DSR(af[0], aA1, 0); DSR(af[1], aA1, 1024);
        DSR(af[2], aA1, 2048); DSR(af[3], aA1, 3072);
        asm volatile("s_waitcnt lgkmcnt(8)");  // ag done (bg+af may fly)
        __builtin_amdgcn_sched_barrier(0);
        __builtin_amdgcn_s_setprio(1);
#pragma unroll
        for (int a = 0; a < 4; ++a)
#pragma unroll
            for (int b = 0; b < 4; ++b)
                acc[4 + a][b] = __builtin_amdgcn_mfma_f32_16x16x32_bf16(ag[a], bf[b], acc[4 + a][b], 0, 0, 0);
        __builtin_amdgcn_s_setprio(0);

        DSR(ag[0], aA1, 4096); DSR(ag[1], aA1, 5120);
        DSR(ag[2], aA1, 6144); DSR(ag[3], aA1, 7168);
        asm volatile("s_waitcnt lgkmcnt(4)");  // bg+af (ksub1) done
        __builtin_amdgcn_sched_barrier(0);
        __builtin_amdgcn_s_setprio(1);
#pragma unroll
        for (int a = 0; a < 4; ++a)
#pragma unroll
            for (int b = 0; b < 4; ++b)
                acc[a][b] = __builtin_amdgcn_mfma_f32_16x16x32_bf16(af[a], bg[b], acc[a][b], 0, 0, 0);
        __builtin_amdgcn_s_setprio(0);

        asm volatile("s_waitcnt lgkmcnt(0)");  // ag (ksub1) done
        __builtin_amdgcn_sched_barrier(0);
        __builtin_amdgcn_s_setprio(1);
#pragma unroll
        for (int a = 0; a < 4; ++a)
#pragma unroll
            for (int b = 0; b < 4; ++b)
                acc[4 + a][b] = __builtin_amdgcn_mfma_f32_16x16x32_bf16(ag[a], bg[b], acc[4 + a][b], 0, 0, 0);
        __builtin_amdgcn_s_setprio(0);
    }
    __syncthreads();                           // all LDS reads done; reuse as scratch

    // ---- epilogue: identical to gemm_tiled ----
    constexpr int ES = 72;
    float bv[4];
#pragma unroll
    for (int b = 0; b < 4; ++b) bv[b] = bias[bn + wn * 64 + b * 16 + lane16];
    u16* scr = ((u16*)sB) + w * (16 * ES);
#pragma unroll
    for (int a = 0; a < 8; ++a) {
#pragma unroll
        for (int b = 0; b < 4; ++b)
#pragma unroll
            for (int r = 0; r < 4; ++r) {
                float v = fmaxf(acc[a][b][r] + bv[b], 0.f);
                scr[(quad * 4 + r) * ES + b * 16 + lane16] = f2bf(v);
            }
#pragma unroll
        for (int ch = 0; ch < 2; ++ch) {
            int row = ch * 8 + (lane >> 3), colc = (lane & 7) * 8;
            short8 v = *(const short8*)(scr + row * ES + colc);
            *(short8*)(Cc + (size_t)(bm + wm * 128 + a * 16 + row) * 1024 + bn + wn * 64 + colc) = v;
        }
    }
}

// ---------------------------------------------------------------------------
// Fused GEMM3 + coupling: tall-skinny streaming form (round-9, kept).
// B (wst, 128 KB) staged to LDS once; A streams global->register; 32
// barrier-free K-steps; coupling/stats tail unchanged.
// ---------------------------------------------------------------------------
__global__ __launch_bounds__(512)
void gemm3_coupling(const u16* __restrict__ A,    // h2 chunk [CH][1024]
                    const u16* __restrict__ Bt,   // wst [64][1024]
                    const float* __restrict__ bs, const float* __restrict__ bt,
                    float* __restrict__ x, float* __restrict__ log_det,
                    float* __restrict__ stat_sum, float* __restrict__ stat_sumsq,
                    int keep_off, int row0)
{
    constexpr int ST_STRIDE = 66;
    __shared__ u16 sB[128 * 512];                    // 128 KB: entry e = s*4+j
    __shared__ float ssum[8][64], ssum2[8][64];
    float* sst = (float*)sB;                         // 128*66*4 = 33.8 KB < 128 KB

    const int t = threadIdx.x;
    const int w = t >> 6, lane = t & 63;
    const int lane16 = lane & 15, quad = lane >> 4;
    const int bm = blockIdx.x * 128;

    // ---- stage all of B once: 128 entries (16 KB/wave, 16 gl_lds) ----
#pragma unroll
    for (int r = 0; r < 16; ++r) {
        int e = r * 8 + w;                           // s = e>>2, j = e&3
        int s = e >> 2, j = e & 3;
        const u16* g = Bt + (size_t)(j * 16 + lane16) * HH + s * 32 + quad * 8;
        gl_lds16(g, &sB[e * 512]);
    }

    f32x4 acc[4];
#pragma unroll
    for (int j = 0; j < 4; ++j) acc[j] = (f32x4){0.f, 0.f, 0.f, 0.f};

    const u16* Arow = A + (size_t)(bm + w * 16 + lane16) * HH + quad * 8;

    __syncthreads();                                 // B staged (drains DMA)

    // ---- main loop: 32 K-steps of 32, no barriers ----
#pragma unroll 4
    for (int s = 0; s < 32; ++s) {
        short8 af = *(const short8*)(Arow + s * 32);
        const u16* bb = sB + s * 2048 + lane * 8;    // entry (s*4+0), lane frag
#pragma unroll
        for (int j = 0; j < 4; ++j) {
            short8 bfr = *(const short8*)(bb + j * 512);
            acc[j] = __builtin_amdgcn_mfma_f32_16x16x32_bf16(af, bfr, acc[j], 0, 0, 0);
        }
    }
    __syncthreads();                                 // all B reads done; alias as sst

    // scatter acc -> LDS st tile (128 x 64)
#pragma unroll
    for (int j = 0; j < 4; ++j)
#pragma unroll
        for (int r = 0; r < 4; ++r)
            sst[(w * 16 + quad * 4 + r) * ST_STRIDE + j * 16 + lane16] = acc[j][r];
    __syncthreads();

    // coupling: wave w -> rows [w*16, w*16+16), lane = feature f
    const int f = lane;
    const bool is_chg = ((f & 1) != keep_off);
    const int j = f >> 1;
    float bsj = 0.f, btj = 0.f;
    if (is_chg) { bsj = bs[j]; btj = bt[j]; }

    float lsum = 0.f, lsum2 = 0.f;
    for (int i = 0; i < 16; ++i) {
        int crow = w * 16 + i;
        int grow = row0 + bm + crow;
        float xv = x[(size_t)grow * DD + f];
        float ld = 0.f;
        if (is_chg) {
            float s_raw = sst[crow * ST_STRIDE + j];
            float t_raw = sst[crow * ST_STRIDE + SPLIT + j];
            float ls = tanhf(s_raw + bsj);
            float tv = t_raw + btj;
            xv = xv * expf(ls) + tv;
            x[(size_t)grow * DD + f] = xv;
            ld = ls;
        }
        for (int off = 32; off > 0; off >>= 1) ld += __shfl_down(ld, off, 64);
        if (f == 0) log_det[grow] += ld;
        lsum  += xv;
        lsum2 += xv * xv;
    }

    ssum[w][f]  = lsum;
    ssum2[w][f] = lsum2;
    __syncthreads();
    if (t < 64) {
        float a = 0.f, b = 0.f;
#pragma unroll
        for (int g = 0; g < 8; ++g) { a += ssum[g][t]; b += ssum2[g][t]; }
        atomicAdd(stat_sum + t, a);
        atomicAdd(stat_sumsq + t, b);
    }
}

// ---------------------------------------------------------------------------
// BN normalize (scale/shift computed in-block from raw stats); optionally
// writes bf16 keep-columns of next layer's Ain.
// ---------------------------------------------------------------------------
__global__ __launch_bounds__(256)
void normalize_kernel(const float* __restrict__ xin, float* __restrict__ xout,
                      const float* __restrict__ stat_sum, const float* __restrict__ stat_sumsq,
                      const float* __restrict__ bn_w, const float* __restrict__ bn_b,
                      float* __restrict__ log_det,
                      u16* __restrict__ Ain, int off_next)
{
    __shared__ float sscale[64], sshift[64], scsum;
    int t = threadIdx.x;
    if (t < 64) {
        const float invB = 1.f / (float)BB;
        float mean = stat_sum[t] * invB;
        float var  = stat_sumsq[t] * invB - mean * mean;
        float inv  = rsqrtf(var + EPSV);
        float wv   = bn_w[t];
        float sc   = inv * wv;
        sscale[t] = sc;
        sshift[t] = bn_b[t] - mean * sc;
        float lg = logf(fabsf(wv));
        for (int off = 32; off > 0; off >>= 1) lg += __shfl_down(lg, off, 64);
        if (t == 0) scsum = lg;
    }
    __syncthreads();

    int idx = blockIdx.x * blockDim.x + t;     // over B*64/4
    int f0 = (idx & 15) * 4;
    int row = idx >> 4;
    float4 v = ((const float4*)xin)[idx];
    v.x = v.x * sscale[f0 + 0] + sshift[f0 + 0];
    v.y = v.y * sscale[f0 + 1] + sshift[f0 + 1];
    v.z = v.z * sscale[f0 + 2] + sshift[f0 + 2];
    v.w = v.w * sscale[f0 + 3] + sshift[f0 + 3];
    ((float4*)xout)[idx] = v;
    if ((idx & 15) == 0) log_det[row] += scsum;
    if (Ain) {
        float a0 = off_next ? v.y : v.x;
        float a1 = off_next ? v.w : v.z;
        ushort2 u; u.x = f2bf(a0); u.y = f2bf(a1);
        *(ushort2*)(Ain + (size_t)row * 128 + (f0 >> 1)) = u;
    }
}

// ---------------------------------------------------------------------------
extern "C" void kernel_launch(void* const* d_in, const int* in_sizes, int n_in,
                              void* d_out, int out_size, void* d_ws, size_t ws_size,
                              hipStream_t stream)
{
    const float* z    = (const float*)d_in[0];
    const float* cond = (const float*)d_in[1];
    const float* W1   = (const float*)d_in[2];
    const float* b1   = (const float*)d_in[3];
    const float* W2   = (const float*)d_in[4];
    const float* b2   = (const float*)d_in[5];
    const float* Ws   = (const float*)d_in[6];
    const float* bs   = (const float*)d_in[7];
    const float* Wt   = (const float*)d_in[8];
    const float* bt   = (const float*)d_in[9];
    const float* bn_w = (const float*)d_in[10];
    const float* bn_b = (const float*)d_in[11];

    float* out_x  = (float*)d_out;
    float* out_ld = out_x + (size_t)BB * DD;

    // ---- workspace: fixed part ~30.5 MB + h1/h2 (CH*4 KB) ----
    char* p = (char*)d_ws;
    size_t used = 0;
    auto alloc = [&](size_t bytes) { void* q = p + used; used += (bytes + 255) & ~(size_t)255; return q; };

    float* xbuf = (float*)alloc((size_t)BB * DD * 4);
    u16*   w1t  = (u16*)alloc((size_t)LL * HH * 128 * 2);
    u16*   w2t  = (u16*)alloc((size_t)LL * HH * HH * 2);
    u16*   wstt = (u16*)alloc((size_t)LL * 64 * HH * 2);
    u16*   Ain  = (u16*)alloc((size_t)BB * 128 * 2);
    float* stat_sum   = (float*)alloc(64 * 4);
    float* stat_sumsq = (float*)alloc(64 * 4);

    int CH = BB;
    while (CH > 8192 && used + (size_t)CH * 4096 + 4096 > ws_size) CH >>= 1;
    u16* h1 = (u16*)alloc((size_t)CH * HH * 2);
    u16* h2 = (u16*)alloc((size_t)CH * HH * 2);

    // ---- init ----
    hipMemcpyAsync(xbuf, z, (size_t)BB * DD * sizeof(float), hipMemcpyDeviceToDevice, stream);
    hipMemsetAsync(out_ld, 0, (size_t)BB * sizeof(float), stream);

    transpose_cvt_kernel<<<dim3(128/32, HH/32, LL), 256, 0, stream>>>(
        W1, w1t, NIN, HH, 128, (long long)NIN * HH, (long long)HH * 128);
    transpose_cvt_kernel<<<dim3(HH/32, HH/32, LL), 256, 0, stream>>>(
        W2, w2t, HH, HH, HH, (long long)HH * HH, (long long)HH * HH);
    transpose_cvt_kernel<<<dim3(HH/32, SPLIT/32, LL), 256, 0, stream>>>(
        Ws, wstt, HH, SPLIT, HH, (long long)HH * SPLIT, (long long)64 * HH);
    transpose_cvt_kernel<<<dim3(HH/32, SPLIT/32, LL), 256, 0, stream>>>(
        Wt, wstt + (size_t)SPLIT * HH, HH, SPLIT, HH, (long long)HH * SPLIT, (long long)64 * HH);

    init_ain_cond_kernel<<<BB * 96 / 256, 256, 0, stream>>>(cond, Ain);
    build_keep_kernel<<<BB * 32 / 256, 256, 0, stream>>>(xbuf, Ain, 0);

    for (int l = 0; l < LL; ++l) {
        const int off = l & 1;
        hipMemsetAsync(stat_sum, 0, 2 * 64 * sizeof(float), stream);

        for (int c = 0; c < BB / CH; ++c) {
            const int row0 = c * CH;

            // GEMM1: h1 = relu(Ain @ W1t^T + b1)   M=CH, K=128 (specialized)
            gemm1_once<<<(CH / 256) * 4, 512, 0, stream>>>(
                Ain + (size_t)row0 * 128, w1t + (size_t)l * HH * 128,
                b1 + (size_t)l * HH, h1);

            // GEMM2: h2 = relu(h1 @ W2t^T + b2)    M=CH, K=1024
            gemm_tiled<<<(CH / 256) * 4, 512, 0, stream>>>(
                h1, w2t + (size_t)l * HH * HH,
                b2 + (size_t)l * HH, h2, HH);

            // GEMM3 + coupling fused (streaming, B-in-LDS-once)
            gemm3_coupling<<<CH / 128, 512, 0, stream>>>(
                h2, wstt + (size_t)l * 64 * HH,
                bs + (size_t)l * SPLIT, bt + (size_t)l * SPLIT,
                xbuf, out_ld, stat_sum, stat_sumsq, off, row0);
        }

        float* xout = (l == LL - 1) ? out_x : xbuf;
        u16* ain_next = (l < LL - 1) ? Ain : nullptr;
        normalize_kernel<<<(BB * DD / 4) / 256, 256, 0, stream>>>(
            xbuf, xout, stat_sum, stat_sumsq,
            bn_w + (size_t)l * DD, bn_b + (size_t)l * DD,
            out_ld, ain_next, (l + 1) & 1);
    }
}